// Round 4
// baseline (3114.938 us; speedup 1.0000x reference)
//
#include <hip/hip_runtime.h>
#include <hip/hip_bf16.h>

using bf16 = __hip_bfloat16;

#define N_    16384
#define M_    65536
#define E1_   131072
#define E2_   131072
#define F_    16384
#define ENC_  512
#define DEC_  256
#define HID_  1365
#define CDIV(a,b) (((a)+(b)-1)/(b))

__device__ __forceinline__ float toF(float v){ return v; }
__device__ __forceinline__ float toF(bf16 v){ return __bfloat162float(v); }
__device__ __forceinline__ bf16  toB(float v){ return __float2bfloat16(v); }

// ---------------------------------------------------------------- CSR build
__global__ void count_k(const int* __restrict__ tgt, int* __restrict__ cnt, int E){
    int e = blockIdx.x*256 + threadIdx.x;
    if (e < E) atomicAdd(&cnt[tgt[e]], 1);
}
__global__ void scan_k(const int* __restrict__ cnt, int* __restrict__ off,
                       int* __restrict__ cur, int n){
    __shared__ int lds[1024];
    int t = threadIdx.x;
    int chunk = (n + 1023) >> 10;
    int base = t * chunk;
    int s = 0;
    for (int i = 0; i < chunk; i++){ int idx = base+i; if (idx < n) s += cnt[idx]; }
    lds[t] = s; __syncthreads();
    for (int d = 1; d < 1024; d <<= 1){
        int v = (t >= d) ? lds[t-d] : 0;
        __syncthreads();
        lds[t] += v;
        __syncthreads();
    }
    int excl = (t == 0) ? 0 : lds[t-1];
    for (int i = 0; i < chunk; i++){
        int idx = base+i;
        if (idx < n){ off[idx] = excl; cur[idx] = excl; excl += cnt[idx]; }
    }
    if (t == 1023) off[n] = lds[1023];
}
__global__ void fill_k(const int* __restrict__ tgt, int* __restrict__ cur,
                       int* __restrict__ el, int E){
    int e = blockIdx.x*256 + threadIdx.x;
    if (e < E){ int p = atomicAdd(&cur[tgt[e]], 1); el[p] = e; }
}

// --------------------------------------------- W_comb = W_x2c @ W_attn[256:]
__global__ void wcomb_k(const float* __restrict__ Wx2c, const float* __restrict__ Wattn,
                        const float* __restrict__ bx2c, const float* __restrict__ battn,
                        float* __restrict__ Wc, float* __restrict__ sb){
    int id = blockIdx.x*256 + threadIdx.x;
    if (id < ENC_*8){
        int k = id >> 3, h = id & 7;
        float s = 0.f;
        for (int c = 0; c < DEC_; c++)
            s += Wx2c[k*DEC_ + c] * Wattn[(DEC_+c)*8 + h];
        Wc[id] = s;
    }
    if (id < 8){
        float s = battn[id];
        for (int c = 0; c < DEC_; c++)
            s += bx2c[c] * Wattn[(DEC_+c)*8 + id];
        sb[id] = s;
    }
}

// s_node[n][h] = root[n] @ W_comb + sbias  (folds ctx_i projection + biases)
__global__ void snode_k(const float* __restrict__ root, const float* __restrict__ Wc,
                        const float* __restrict__ sb, float* __restrict__ sn){
    int id = blockIdx.x*256 + threadIdx.x;
    if (id >= N_*8) return;
    int n = id >> 3, h = id & 7;
    float s = sb[h];
    const float* rp = root + (long)n*ENC_;
    for (int k = 0; k < ENC_; k++) s += rp[k] * Wc[k*8 + h];
    sn[id] = s;
}

// ------------------------------------------------------------ generic GEMM
// C[M,N] = A[M,K] @ B[K,N] (+bias) (*mul); f32 accumulate, out bf16 or f32.
template<typename TA, typename TB, int OUT_BF16, int GATHER, int MULEPI>
__launch_bounds__(256)
__global__ void gemm_k(const TA* __restrict__ A, const TB* __restrict__ B,
                       const float* __restrict__ bias, void* __restrict__ Cp,
                       const int* __restrict__ rows, const float* __restrict__ mul,
                       int M, int N, int K, int lda, int ldb){
    __shared__ float As[16][128];
    __shared__ float Bs[16][128];
    int t  = threadIdx.x;
    int tx = t & 15, ty = t >> 4;
    int bn = blockIdx.x * 128, bm = blockIdx.y * 128;
    float acc[8][8] = {};
    int arow  = t >> 1, acol0 = (t & 1) * 8;
    int brow  = t >> 4, bcol0 = (t & 15) * 8;
    long arow_g = bm + arow;
    long asrc = -1;
    if (arow_g < M) asrc = (GATHER ? (long)rows[arow_g] : arow_g) * (long)lda;

    for (int k0 = 0; k0 < K; k0 += 16){
        #pragma unroll
        for (int j = 0; j < 8; j++){
            int kk = k0 + acol0 + j;
            float v = 0.f;
            if (asrc >= 0 && kk < K) v = toF(A[asrc + kk]);
            As[acol0 + j][arow] = v;
        }
        #pragma unroll
        for (int j = 0; j < 8; j++){
            int kk = k0 + brow;
            int nn = bn + bcol0 + j;
            float v = 0.f;
            if (kk < K && nn < N) v = toF(B[(long)kk*ldb + nn]);
            Bs[brow][bcol0 + j] = v;
        }
        __syncthreads();
        #pragma unroll
        for (int kk = 0; kk < 16; kk++){
            float a[8], b[8];
            #pragma unroll
            for (int i = 0; i < 8; i++) a[i] = As[kk][ty*8 + i];
            #pragma unroll
            for (int j = 0; j < 8; j++) b[j] = Bs[kk][tx*8 + j];
            #pragma unroll
            for (int i = 0; i < 8; i++)
                #pragma unroll
                for (int j = 0; j < 8; j++)
                    acc[i][j] += a[i]*b[j];
        }
        __syncthreads();
    }
    #pragma unroll
    for (int i = 0; i < 8; i++){
        long r = bm + ty*8 + i;
        if (r >= M) break;
        #pragma unroll
        for (int j = 0; j < 8; j++){
            long c = bn + tx*8 + j;
            if (c >= N) continue;
            float v = acc[i][j];
            if (bias) v += bias[c];
            if (MULEPI) v *= mul[r*(long)N + c];
            if (OUT_BF16) ((bf16*)Cp)[r*(long)N + c] = toB(v);
            else          ((float*)Cp)[r*(long)N + c] = v;
        }
    }
}

// ------------------------- fused dual GEMM: H = silu(A@B1) * (A@B2), bf16 out
__launch_bounds__(256)
__global__ void gemm_swiglu_k(const bf16* __restrict__ A, const float* __restrict__ B1,
                              const float* __restrict__ B2, bf16* __restrict__ H,
                              int M, int N, int K, int lda, int ldb){
    __shared__ float As[16][128];
    __shared__ float B1s[16][64];
    __shared__ float B2s[16][64];
    int t  = threadIdx.x;
    int tx = t & 15, ty = t >> 4;
    int bn = blockIdx.x * 64, bm = blockIdx.y * 128;
    float acc1[8][4] = {}, acc2[8][4] = {};
    int arow  = t >> 1, acol0 = (t & 1) * 8;
    int brow  = t >> 4, bcol0 = (t & 15) * 4;
    long arow_g = bm + arow;
    long asrc = (arow_g < M) ? arow_g*(long)lda : -1;

    for (int k0 = 0; k0 < K; k0 += 16){
        #pragma unroll
        for (int j = 0; j < 8; j++){
            int kk = k0 + acol0 + j;
            float v = 0.f;
            if (asrc >= 0 && kk < K) v = toF(A[asrc + kk]);
            As[acol0 + j][arow] = v;
        }
        #pragma unroll
        for (int j = 0; j < 4; j++){
            int kk = k0 + brow;
            int nn = bn + bcol0 + j;
            float v1 = 0.f, v2 = 0.f;
            if (kk < K && nn < N){
                v1 = B1[(long)kk*ldb + nn];
                v2 = B2[(long)kk*ldb + nn];
            }
            B1s[brow][bcol0 + j] = v1;
            B2s[brow][bcol0 + j] = v2;
        }
        __syncthreads();
        #pragma unroll
        for (int kk = 0; kk < 16; kk++){
            float a[8], b1[4], b2[4];
            #pragma unroll
            for (int i = 0; i < 8; i++) a[i] = As[kk][ty*8 + i];
            #pragma unroll
            for (int j = 0; j < 4; j++){ b1[j] = B1s[kk][tx*4 + j]; b2[j] = B2s[kk][tx*4 + j]; }
            #pragma unroll
            for (int i = 0; i < 8; i++)
                #pragma unroll
                for (int j = 0; j < 4; j++){
                    acc1[i][j] += a[i]*b1[j];
                    acc2[i][j] += a[i]*b2[j];
                }
        }
        __syncthreads();
    }
    #pragma unroll
    for (int i = 0; i < 8; i++){
        long r = bm + ty*8 + i;
        if (r >= M) break;
        #pragma unroll
        for (int j = 0; j < 4; j++){
            long c = bn + tx*4 + j;
            if (c >= N) continue;
            float g = acc1[i][j], u = acc2[i][j];
            float s = g / (1.f + expf(-g));
            H[r*(long)N + c] = toB(s*u);
        }
    }
}

// ---------------- stage 1: HGATConv via per-head weighted feedback sums
// agg[i, h*64+d] = (T[i,h,:] @ W_c2x[:, h*64+d]) + (1-a_self)*b_c2x + a_self*root
__launch_bounds__(256)
__global__ void stage1_k(const float* __restrict__ root, const float* __restrict__ fb,
                         const float* __restrict__ sfb, const float* __restrict__ sn,
                         const int* __restrict__ fbj, const int* __restrict__ off,
                         const int* __restrict__ el, const float* __restrict__ Wc2x,
                         const float* __restrict__ bc2x, const float* __restrict__ gn,
                         bf16* __restrict__ x1){
    int i = blockIdx.x, t = threadIdx.x;
    __shared__ float T[8][256];
    __shared__ float sm[8], mh[8], sh[8], asf[8];
    __shared__ float al[64][8];
    __shared__ int   ej[64];
    __shared__ float red[256];
    if (t < 8) sm[t] = sn[i*8 + t];
    #pragma unroll
    for (int h = 0; h < 8; h++) T[h][t] = 0.f;
    __syncthreads();
    int e0 = off[i], e1 = off[i+1];
    if (t < 8){
        float smv = sm[t];
        float self = smv >= 0.f ? smv : 0.2f*smv;
        float mv = self;
        for (int e = e0; e < e1; e++){
            int j = fbj[el[e]];
            float v = sfb[j*8 + t] + smv; v = v >= 0.f ? v : 0.2f*v;
            mv = fmaxf(mv, v);
        }
        float sv = expf(self - mv);
        for (int e = e0; e < e1; e++){
            int j = fbj[el[e]];
            float v = sfb[j*8 + t] + smv; v = v >= 0.f ? v : 0.2f*v;
            sv += expf(v - mv);
        }
        mh[t] = mv; sh[t] = sv; asf[t] = expf(self - mv)/sv;
    }
    __syncthreads();
    for (int cb = e0; cb < e1; cb += 64){
        int cn = min(e1, cb + 64) - cb;
        if (t < cn) ej[t] = fbj[el[cb + t]];
        __syncthreads();
        for (int x = t; x < cn*8; x += 256){
            int e_l = x >> 3, hh = x & 7;
            int j = ej[e_l];
            float v = sfb[j*8 + hh] + sm[hh]; v = v >= 0.f ? v : 0.2f*v;
            al[e_l][hh] = expf(v - mh[hh])/sh[hh];
        }
        __syncthreads();
        for (int e = 0; e < cn; e++){
            float fbv = fb[(long)ej[e]*DEC_ + t];
            #pragma unroll
            for (int h = 0; h < 8; h++)
                T[h][t] += al[e][h] * fbv;
        }
        __syncthreads();
    }
    float rr[2]; float ss = 0.f;
    #pragma unroll
    for (int q = 0; q < 2; q++){
        int o = t + q*256;
        int h = o >> 6;
        float acc = 0.f;
        for (int c2 = 0; c2 < 256; c2++)
            acc += T[h][c2] * Wc2x[(long)c2*ENC_ + o];
        float a_self = asf[h];
        float rt = root[(long)i*ENC_ + o];
        float v = rt*(1.f + a_self) + acc + (1.f - a_self)*bc2x[o];
        rr[q] = v; ss += v*v;
    }
    red[t] = ss; __syncthreads();
    for (int s2 = 128; s2 > 0; s2 >>= 1){ if (t < s2) red[t] += red[t+s2]; __syncthreads(); }
    float sc = rsqrtf(red[0]/512.f + 1e-6f);
    #pragma unroll
    for (int q = 0; q < 2; q++){
        int o = t + q*256;
        x1[(long)i*ENC_ + o] = toB(rr[q]*sc*gn[o]);
    }
}

// ---------------- stage 2 (per 4-head group): edge MHA, writes agg2 slice
#define CH2 32
__launch_bounds__(256)
__global__ void stage2_k(const bf16* __restrict__ qkvh, const float* __restrict__ attr,
                         const int* __restrict__ sj, const int* __restrict__ off,
                         const int* __restrict__ el, bf16* __restrict__ agg2){
    int i = blockIdx.x, t = threadIdx.x;
    __shared__ float qi[256];
    __shared__ float m[4], s[4], fac[4];
    __shared__ float p[CH2][4];
    __shared__ int ejs[CH2], ega[CH2];
    qi[t] = toF(qkvh[(long)i*768 + (t>>6)*192 + (t&63)*3]);   // q (comp 0)
    if (t < 4){ m[t] = -3.0e38f; s[t] = 0.f; }
    __syncthreads();
    int e0 = off[i], e1 = off[i+1];
    int c = t, h = c >> 6, d = c & 63;
    float acc = 0.f;
    for (int cb = e0; cb < e1; cb += CH2){
        int cn = min(e1, cb + CH2) - cb;
        if (t < cn){ int eg = el[cb + t]; ejs[t] = sj[eg]; ega[t] = eg; }
        __syncthreads();
        int e_l = t >> 2, hh = t & 3;
        if (e_l < cn){
            int sjn = ejs[e_l];
            long kb = (long)sjn*768 + hh*192 + 1;      // k (comp 1)
            long ab = (long)ega[e_l]*64;
            float dot = 0.f;
            #pragma unroll
            for (int dd = 0; dd < 64; dd++)
                dot += qi[hh*64 + dd] * toF(qkvh[kb + dd*3]) * attr[ab + dd];
            p[e_l][hh] = dot * 0.125f;
        }
        __syncthreads();
        if (t < 4){
            float mo = m[t], mn = mo;
            for (int e = 0; e < cn; e++) mn = fmaxf(mn, p[e][t]);
            float f = (mo > -1.0e38f) ? expf(mo - mn) : 0.f;
            float sv = s[t]*f;
            for (int e = 0; e < cn; e++){ float pe = expf(p[e][t] - mn); p[e][t] = pe; sv += pe; }
            m[t] = mn; s[t] = sv; fac[t] = f;
        }
        __syncthreads();
        float f = fac[h];
        acc *= f;
        for (int e = 0; e < cn; e++)
            acc += p[e][h] * toF(qkvh[(long)ejs[e]*768 + h*192 + d*3 + 2]);  // v
        __syncthreads();
    }
    float sv = s[h];
    float inv = (sv > 0.f) ? 1.f/sv : 0.f;
    agg2[(long)i*ENC_ + c] = toB(acc*inv);
}

// ---------------- residual RMSNorm: x = rmsnorm(x + a, g)  (in-place-safe)
__launch_bounds__(128)
__global__ void rms2_k(bf16* __restrict__ x, const bf16* __restrict__ a,
                       const float* __restrict__ g){
    int i = blockIdx.x, t = threadIdx.x;
    __shared__ float red[128];
    float r[4]; float ss = 0.f;
    long base = (long)i*ENC_ + t*4;
    #pragma unroll
    for (int j = 0; j < 4; j++){ float v = toF(x[base+j]) + toF(a[base+j]); r[j] = v; ss += v*v; }
    red[t] = ss; __syncthreads();
    for (int s2 = 64; s2 > 0; s2 >>= 1){ if (t < s2) red[t] += red[t+s2]; __syncthreads(); }
    float sc = rsqrtf(red[0]/512.f + 1e-6f);
    #pragma unroll
    for (int j = 0; j < 4; j++) x[base+j] = toB(r[j]*sc*g[t*4 + j]);
}

// ---------------- final residual RMSNorm -> f32 d_out
__launch_bounds__(128)
__global__ void rms_k(const bf16* __restrict__ x, const bf16* __restrict__ y,
                      const float* __restrict__ g, float* __restrict__ out){
    int i = blockIdx.x, t = threadIdx.x;
    __shared__ float red[128];
    float r[4]; float ss = 0.f;
    long base = (long)i*ENC_ + t*4;
    #pragma unroll
    for (int j = 0; j < 4; j++){ float v = toF(x[base+j]) + toF(y[base+j]); r[j] = v; ss += v*v; }
    red[t] = ss; __syncthreads();
    for (int s2 = 64; s2 > 0; s2 >>= 1){ if (t < s2) red[t] += red[t+s2]; __syncthreads(); }
    float sc = rsqrtf(red[0]/512.f + 1e-6f);
    #pragma unroll
    for (int j = 0; j < 4; j++) out[base+j] = r[j]*sc*g[t*4 + j];
}

// ============================================================== launcher
// Arena (59.8 MB), lifetime-overlaid:
//  R1 [0, 24M): qkv_h [N,768]bf16 -> hbuf chunk [8192,1365]bf16
//  R2 [24M, 40M): x1 bf16 (in-place -> x2)
//  R3 [40M, 56M): agg2 bf16 -> y bf16
//  smalls [56M, 59.8M): sfb, snode, wcomb, sbias, cnt, cur, off1, off2, el1, el2
extern "C" void kernel_launch(void* const* d_in, const int* in_sizes, int n_in,
                              void* d_out, int out_size, void* d_ws, size_t ws_size,
                              hipStream_t stream){
    const float* root  = (const float*)d_in[0];
    const float* fb    = (const float*)d_in[1];
    const int*   fbidx = (const int*)d_in[2];   // [0..E1)=j, [E1..2E1)=i
    const float* fmaps = (const float*)d_in[3];
    const int*   rfi   = (const int*)d_in[4];
    const int*   reidx = (const int*)d_in[5];   // [0..E2)=sj, [E2..2E2)=si
    const float* rattr = (const float*)d_in[6];
    const float* Wc2x  = (const float*)d_in[7];
    const float* bc2x  = (const float*)d_in[8];
    const float* Wx2c  = (const float*)d_in[9];
    const float* bx2c  = (const float*)d_in[10];
    const float* Wattn = (const float*)d_in[11];
    const float* battn = (const float*)d_in[12];
    const float* Wqkv  = (const float*)d_in[13];
    const float* bqkv  = (const float*)d_in[14];
    const float* Wgate = (const float*)d_in[15];
    const float* Wup   = (const float*)d_in[16];
    const float* Wout  = (const float*)d_in[17];
    const float* Wfr   = (const float*)d_in[18];
    const float* bfr   = (const float*)d_in[19];
    const float* gnode = (const float*)d_in[20];
    const float* groot = (const float*)d_in[21];
    const float* gffn  = (const float*)d_in[22];

    float* out_x  = (float*)d_out;
    float* out_fr = out_x + (long)N_*ENC_;

    char* ws = (char*)d_ws;
    bf16*  qkvh  = (bf16*)(ws);                    // R1
    bf16*  hbuf  = (bf16*)(ws);                    // R1 (after qkv dead)
    bf16*  x1    = (bf16*)(ws + 25165824);         // R2
    bf16*  agg2  = (bf16*)(ws + 41943040);         // R3
    bf16*  yb    = agg2;
    float* sfb   = (float*)(ws + 58720256);
    float* snode = (float*)(ws + 60817408);
    float* wcomb = (float*)(ws + 61341696);
    float* sbias = (float*)(ws + 61358080);
    int*   cnt   = (int*)  (ws + 61358336);
    int*   cur   = (int*)  (ws + 61423872);
    int*   off1  = (int*)  (ws + 61489408);
    int*   off2  = (int*)  (ws + 61555200);
    int*   el1   = (int*)  (ws + 61620992);
    int*   el2   = (int*)  (ws + 62145280);

    // ---- CSR builds
    hipMemsetAsync(cnt, 0, N_*4, stream);
    count_k<<<CDIV(E1_,256),256,0,stream>>>(fbidx + E1_, cnt, E1_);
    scan_k<<<1,1024,0,stream>>>(cnt, off1, cur, N_);
    fill_k<<<CDIV(E1_,256),256,0,stream>>>(fbidx + E1_, cur, el1, E1_);
    hipMemsetAsync(cnt, 0, N_*4, stream);
    count_k<<<CDIV(E2_,256),256,0,stream>>>(reidx + E2_, cnt, E2_);
    scan_k<<<1,1024,0,stream>>>(cnt, off2, cur, N_);
    fill_k<<<CDIV(E2_,256),256,0,stream>>>(reidx + E2_, cur, el2, E2_);

    // ---- stage-1 precomputes
    wcomb_k<<<16,256,0,stream>>>(Wx2c, Wattn, bx2c, battn, wcomb, sbias);
    snode_k<<<CDIV(N_*8,256),256,0,stream>>>(root, wcomb, sbias, snode);
    { dim3 g(1, CDIV(M_,128));   // sfb = feedback @ W_attn[:256]  [M,8] f32
      gemm_k<float,float,0,0,0><<<g,256,0,stream>>>(fb, Wattn, nullptr, sfb,
                                                    nullptr, nullptr, M_, 8, DEC_, DEC_, 8); }
    stage1_k<<<N_,256,0,stream>>>(root, fb, sfb, snode, fbidx, off1, el1,
                                  Wc2x, bc2x, gnode, x1);

    // ---- stage 2: two head-group passes
    for (int p = 0; p < 2; p++){
        dim3 g(CDIV(768,128), CDIV(N_,128));
        gemm_k<bf16,float,1,0,0><<<g,256,0,stream>>>(x1, Wqkv + p*768, bqkv + p*768, qkvh,
                                                     nullptr, nullptr, N_, 768, ENC_, ENC_, 1536);
        stage2_k<<<N_,256,0,stream>>>(qkvh, rattr, reidx, off2, el2, agg2 + p*256);
    }
    rms2_k<<<N_,128,0,stream>>>(x1, agg2, groot);   // x1 -> x2 in-place

    // ---- FFN in two row-chunks (R1 holds h-chunk)
    for (int rc = 0; rc < 2; rc++){
        long ro = (long)rc*8192;
        { dim3 g(CDIV(HID_,64), CDIV(8192,128));
          gemm_swiglu_k<<<g,256,0,stream>>>(x1 + ro*ENC_, Wgate, Wup, hbuf,
                                            8192, HID_, ENC_, ENC_, HID_); }
        { dim3 g(CDIV(ENC_,128), CDIV(8192,128));
          gemm_k<bf16,float,1,0,0><<<g,256,0,stream>>>(hbuf, Wout, nullptr, yb + ro*ENC_,
                                                       nullptr, nullptr, 8192, ENC_, HID_, HID_, ENC_); }
    }
    rms_k<<<N_,128,0,stream>>>(x1, yb, gffn, out_x);

    // ---- fringe decode (gather f32 rows from d_out, multiply fringe_maps)
    { dim3 g(CDIV(DEC_,128), CDIV(F_,128));
      gemm_k<float,float,0,1,1><<<g,256,0,stream>>>(out_x, Wfr, bfr, out_fr, rfi, fmaps,
                                                    F_, DEC_, ENC_, ENC_, DEC_); }
}

// Round 5
// 1392.886 us; speedup vs baseline: 2.2363x; 2.2363x over previous
//
#include <hip/hip_runtime.h>
#include <hip/hip_bf16.h>

using bf16 = __hip_bfloat16;
typedef __attribute__((ext_vector_type(8))) short s8v;   // 8 bf16 (4 VGPRs)
typedef __attribute__((ext_vector_type(4))) float f4v;   // 4 f32 acc

#define N_    16384
#define M_    65536
#define E1_   131072
#define E2_   131072
#define F_    16384
#define ENC_  512
#define DEC_  256
#define HID_  1365
#define HIDP  1376   // HID padded to 16B-aligned row (8-elem multiple)
#define CDIV(a,b) (((a)+(b)-1)/(b))

__device__ __forceinline__ float toF(float v){ return v; }
__device__ __forceinline__ float toF(bf16 v){ return __bfloat162float(v); }
__device__ __forceinline__ bf16  toB(float v){ return __float2bfloat16(v); }

// ---------------------------------------------------------------- CSR build
__global__ void count_k(const int* __restrict__ tgt, int* __restrict__ cnt, int E){
    int e = blockIdx.x*256 + threadIdx.x;
    if (e < E) atomicAdd(&cnt[tgt[e]], 1);
}
__global__ void scan_k(const int* __restrict__ cnt, int* __restrict__ off,
                       int* __restrict__ cur, int n){
    __shared__ int lds[1024];
    int t = threadIdx.x;
    int chunk = (n + 1023) >> 10;
    int base = t * chunk;
    int s = 0;
    for (int i = 0; i < chunk; i++){ int idx = base+i; if (idx < n) s += cnt[idx]; }
    lds[t] = s; __syncthreads();
    for (int d = 1; d < 1024; d <<= 1){
        int v = (t >= d) ? lds[t-d] : 0;
        __syncthreads();
        lds[t] += v;
        __syncthreads();
    }
    int excl = (t == 0) ? 0 : lds[t-1];
    for (int i = 0; i < chunk; i++){
        int idx = base+i;
        if (idx < n){ off[idx] = excl; cur[idx] = excl; excl += cnt[idx]; }
    }
    if (t == 1023) off[n] = lds[1023];
}
__global__ void fill_k(const int* __restrict__ tgt, int* __restrict__ cur,
                       int* __restrict__ el, int E){
    int e = blockIdx.x*256 + threadIdx.x;
    if (e < E){ int p = atomicAdd(&cur[tgt[e]], 1); el[p] = e; }
}

// -------------------------------- transpose f32 [K,N] -> bf16 BT [N,ldo]
__global__ void prepT_k(const float* __restrict__ in, bf16* __restrict__ out,
                        int N, int K, int ldo){
    int id = blockIdx.x*256 + threadIdx.x;
    if (id >= N*ldo) return;
    int n = id / ldo, k = id - n*ldo;
    out[id] = toB(k < K ? in[(long)k*N + n] : 0.f);
}

// --------------------------------------------- W_comb = W_x2c @ W_attn[256:]
__global__ void wcomb_k(const float* __restrict__ Wx2c, const float* __restrict__ Wattn,
                        const float* __restrict__ bx2c, const float* __restrict__ battn,
                        float* __restrict__ Wc, float* __restrict__ sb){
    int id = blockIdx.x*256 + threadIdx.x;
    if (id < ENC_*8){
        int k = id >> 3, h = id & 7;
        float s = 0.f;
        for (int c = 0; c < DEC_; c++)
            s += Wx2c[k*DEC_ + c] * Wattn[(DEC_+c)*8 + h];
        Wc[id] = s;
    }
    if (id < 8){
        float s = battn[id];
        for (int c = 0; c < DEC_; c++)
            s += bx2c[c] * Wattn[(DEC_+c)*8 + id];
        sb[id] = s;
    }
}

// s_node[n][h] = root[n] @ W_comb + sbias
__global__ void snode_k(const float* __restrict__ root, const float* __restrict__ Wc,
                        const float* __restrict__ sb, float* __restrict__ sn){
    int id = blockIdx.x*256 + threadIdx.x;
    if (id >= N_*8) return;
    int n = id >> 3, h = id & 7;
    float s = sb[h];
    const float* rp = root + (long)n*ENC_;
    for (int k = 0; k < ENC_; k++) s += rp[k] * Wc[k*8 + h];
    sn[id] = s;
}

// =================================================== MFMA GEMM (bf16 NT)
// C[M,N] = A[M,K] @ BT[N,K]^T (+bias) (*mul); DUAL: C = silu(A@B1)*(A@B2).
// A: bf16 or f32 (converted in staging), optional row-gather.
template<typename TA, int DUAL, int GATHER, int MULEPI, int OUT_BF16>
__launch_bounds__(256, 2)
__global__ void mgemm_k(const TA* __restrict__ A, const bf16* __restrict__ BT1,
                        const bf16* __restrict__ BT2, const float* __restrict__ bias,
                        void* __restrict__ Cp, const int* __restrict__ rows,
                        const float* __restrict__ mul,
                        int M, int N, int K, int lda, int ldbt, int ldc){
    __shared__ bf16 As [128][40];
    __shared__ bf16 Bs1[128][40];
    __shared__ bf16 Bs2[DUAL ? 128 : 1][40];
    const int t = threadIdx.x;
    const int bn = blockIdx.x * 128, bm = blockIdx.y * 128;
    const int lane = t & 63, fr = lane & 15, q = lane >> 4, q8 = q*8;
    const int wv = t >> 6, wr = wv >> 1, wc = wv & 1;

    // per-thread staging row offsets (2 chunks of 8 elems each per tile)
    long aoff[2], boff[2];
    #pragma unroll
    for (int it = 0; it < 2; it++){
        int c = t + it*256, r = c >> 2;
        int gr = bm + r;
        aoff[it] = -1;
        if (gr < M) aoff[it] = (GATHER ? (long)rows[gr] : (long)gr) * (long)lda;
        int gn = bn + r;
        boff[it] = (gn < N) ? (long)gn * (long)ldbt : -1;
    }

    f4v z = {0.f, 0.f, 0.f, 0.f};
    f4v acc1[4][4], acc2[4][4];
    #pragma unroll
    for (int i = 0; i < 4; i++)
        #pragma unroll
        for (int j = 0; j < 4; j++){ acc1[i][j] = z; acc2[i][j] = z; }

    for (int k0 = 0; k0 < K; k0 += 32){
        #pragma unroll
        for (int it = 0; it < 2; it++){
            int c = t + it*256, r = c >> 2, co = (c & 3)*8, kk = k0 + co;
            // ---- A tile
            if (aoff[it] >= 0 && kk + 8 <= K){
                if constexpr (sizeof(TA) == 2){
                    *(uint4*)&As[r][co] = *(const uint4*)(A + aoff[it] + kk);
                } else {
                    const float* p = (const float*)A + aoff[it] + kk;
                    float4 v0 = *(const float4*)p, v1 = *(const float4*)(p+4);
                    bf16* d = &As[r][co];
                    d[0]=toB(v0.x); d[1]=toB(v0.y); d[2]=toB(v0.z); d[3]=toB(v0.w);
                    d[4]=toB(v1.x); d[5]=toB(v1.y); d[6]=toB(v1.z); d[7]=toB(v1.w);
                }
            } else {
                #pragma unroll
                for (int j = 0; j < 8; j++){
                    float v = (aoff[it] >= 0 && kk + j < K) ? toF(A[aoff[it] + kk + j]) : 0.f;
                    As[r][co + j] = toB(v);
                }
            }
            // ---- B tiles
            if (boff[it] >= 0 && kk + 8 <= K){
                *(uint4*)&Bs1[r][co] = *(const uint4*)(BT1 + boff[it] + kk);
                if (DUAL) *(uint4*)&Bs2[r][co] = *(const uint4*)(BT2 + boff[it] + kk);
            } else {
                #pragma unroll
                for (int j = 0; j < 8; j++){
                    bool ok = (boff[it] >= 0 && kk + j < K);
                    Bs1[r][co + j] = ok ? BT1[boff[it] + kk + j] : toB(0.f);
                    if (DUAL) Bs2[r][co + j] = ok ? BT2[boff[it] + kk + j] : toB(0.f);
                }
            }
        }
        __syncthreads();
        s8v av[4], bv1[4], bv2[4];
        #pragma unroll
        for (int mt = 0; mt < 4; mt++) av[mt] = *(const s8v*)&As[wr*64 + mt*16 + fr][q8];
        #pragma unroll
        for (int nt = 0; nt < 4; nt++){
            bv1[nt] = *(const s8v*)&Bs1[wc*64 + nt*16 + fr][q8];
            if (DUAL) bv2[nt] = *(const s8v*)&Bs2[wc*64 + nt*16 + fr][q8];
        }
        #pragma unroll
        for (int mt = 0; mt < 4; mt++)
            #pragma unroll
            for (int nt = 0; nt < 4; nt++){
                acc1[mt][nt] = __builtin_amdgcn_mfma_f32_16x16x32_bf16(av[mt], bv1[nt], acc1[mt][nt], 0, 0, 0);
                if (DUAL)
                    acc2[mt][nt] = __builtin_amdgcn_mfma_f32_16x16x32_bf16(av[mt], bv2[nt], acc2[mt][nt], 0, 0, 0);
            }
        __syncthreads();
    }

    // epilogue: C/D layout col = lane&15, row = quad*4 + r
    #pragma unroll
    for (int mt = 0; mt < 4; mt++){
        int row0 = bm + wr*64 + mt*16 + q*4;
        #pragma unroll
        for (int nt = 0; nt < 4; nt++){
            int col = bn + wc*64 + nt*16 + fr;
            if (col >= N) continue;
            #pragma unroll
            for (int r = 0; r < 4; r++){
                int rr = row0 + r;
                if (rr >= M) continue;
                float v = acc1[mt][nt][r];
                if (DUAL){
                    float u = acc2[mt][nt][r];
                    v = (v / (1.f + expf(-v))) * u;
                }
                if (bias) v += bias[col];
                if (MULEPI) v *= mul[(long)rr*ldc + col];
                if (OUT_BF16) ((bf16*)Cp)[(long)rr*ldc + col] = toB(v);
                else          ((float*)Cp)[(long)rr*ldc + col] = v;
            }
        }
    }
}

// ---------------- stage 1: HGATConv via per-head weighted feedback sums
__launch_bounds__(256)
__global__ void stage1_k(const float* __restrict__ root, const float* __restrict__ fb,
                         const float* __restrict__ sfb, const float* __restrict__ sn,
                         const int* __restrict__ fbj, const int* __restrict__ off,
                         const int* __restrict__ el, const float* __restrict__ Wc2x,
                         const float* __restrict__ bc2x, const float* __restrict__ gn,
                         bf16* __restrict__ x1){
    int i = blockIdx.x, t = threadIdx.x;
    __shared__ float T[8][256];
    __shared__ float sm[8], mh[8], sh[8], asf[8];
    __shared__ float al[64][8];
    __shared__ int   ej[64];
    __shared__ float red[256];
    if (t < 8) sm[t] = sn[i*8 + t];
    #pragma unroll
    for (int h = 0; h < 8; h++) T[h][t] = 0.f;
    __syncthreads();
    int e0 = off[i], e1 = off[i+1];
    if (t < 8){
        float smv = sm[t];
        float self = smv >= 0.f ? smv : 0.2f*smv;
        float mv = self;
        for (int e = e0; e < e1; e++){
            int j = fbj[el[e]];
            float v = sfb[j*8 + t] + smv; v = v >= 0.f ? v : 0.2f*v;
            mv = fmaxf(mv, v);
        }
        float sv = expf(self - mv);
        for (int e = e0; e < e1; e++){
            int j = fbj[el[e]];
            float v = sfb[j*8 + t] + smv; v = v >= 0.f ? v : 0.2f*v;
            sv += expf(v - mv);
        }
        mh[t] = mv; sh[t] = sv; asf[t] = expf(self - mv)/sv;
    }
    __syncthreads();
    for (int cb = e0; cb < e1; cb += 64){
        int cn = min(e1, cb + 64) - cb;
        if (t < cn) ej[t] = fbj[el[cb + t]];
        __syncthreads();
        for (int x = t; x < cn*8; x += 256){
            int e_l = x >> 3, hh = x & 7;
            int j = ej[e_l];
            float v = sfb[j*8 + hh] + sm[hh]; v = v >= 0.f ? v : 0.2f*v;
            al[e_l][hh] = expf(v - mh[hh])/sh[hh];
        }
        __syncthreads();
        for (int e = 0; e < cn; e++){
            float fbv = fb[(long)ej[e]*DEC_ + t];
            #pragma unroll
            for (int h = 0; h < 8; h++)
                T[h][t] += al[e][h] * fbv;
        }
        __syncthreads();
    }
    float rr[2]; float ss = 0.f;
    #pragma unroll
    for (int qq = 0; qq < 2; qq++){
        int o = t + qq*256;
        int h = o >> 6;
        float acc = 0.f;
        for (int c2 = 0; c2 < 256; c2++)
            acc += T[h][c2] * Wc2x[(long)c2*ENC_ + o];
        float a_self = asf[h];
        float rt = root[(long)i*ENC_ + o];
        float v = rt*(1.f + a_self) + acc + (1.f - a_self)*bc2x[o];
        rr[qq] = v; ss += v*v;
    }
    red[t] = ss; __syncthreads();
    for (int s2 = 128; s2 > 0; s2 >>= 1){ if (t < s2) red[t] += red[t+s2]; __syncthreads(); }
    float sc = rsqrtf(red[0]/512.f + 1e-6f);
    #pragma unroll
    for (int qq = 0; qq < 2; qq++){
        int o = t + qq*256;
        x1[(long)i*ENC_ + o] = toB(rr[qq]*sc*gn[o]);
    }
}

// ---------------- stage 2 (per 4-head group): edge MHA, writes agg2 slice
#define CH2 32
__launch_bounds__(256)
__global__ void stage2_k(const bf16* __restrict__ qkvh, const float* __restrict__ attr,
                         const int* __restrict__ sj, const int* __restrict__ off,
                         const int* __restrict__ el, bf16* __restrict__ agg2){
    int i = blockIdx.x, t = threadIdx.x;
    __shared__ float qi[256];
    __shared__ float m[4], s[4], fac[4];
    __shared__ float p[CH2][4];
    __shared__ int ejs[CH2], ega[CH2];
    qi[t] = toF(qkvh[(long)i*768 + (t>>6)*192 + (t&63)*3]);   // q (comp 0)
    if (t < 4){ m[t] = -3.0e38f; s[t] = 0.f; }
    __syncthreads();
    int e0 = off[i], e1 = off[i+1];
    int c = t, h = c >> 6, d = c & 63;
    float acc = 0.f;
    for (int cb = e0; cb < e1; cb += CH2){
        int cn = min(e1, cb + CH2) - cb;
        if (t < cn){ int eg = el[cb + t]; ejs[t] = sj[eg]; ega[t] = eg; }
        __syncthreads();
        int e_l = t >> 2, hh = t & 3;
        if (e_l < cn){
            int sjn = ejs[e_l];
            long kb = (long)sjn*768 + hh*192 + 1;      // k (comp 1)
            long ab = (long)ega[e_l]*64;
            float dot = 0.f;
            #pragma unroll
            for (int dd = 0; dd < 64; dd++)
                dot += qi[hh*64 + dd] * toF(qkvh[kb + dd*3]) * attr[ab + dd];
            p[e_l][hh] = dot * 0.125f;
        }
        __syncthreads();
        if (t < 4){
            float mo = m[t], mn = mo;
            for (int e = 0; e < cn; e++) mn = fmaxf(mn, p[e][t]);
            float f = (mo > -1.0e38f) ? expf(mo - mn) : 0.f;
            float sv = s[t]*f;
            for (int e = 0; e < cn; e++){ float pe = expf(p[e][t] - mn); p[e][t] = pe; sv += pe; }
            m[t] = mn; s[t] = sv; fac[t] = f;
        }
        __syncthreads();
        float f = fac[h];
        acc *= f;
        for (int e = 0; e < cn; e++)
            acc += p[e][h] * toF(qkvh[(long)ejs[e]*768 + h*192 + d*3 + 2]);  // v
        __syncthreads();
    }
    float sv = s[h];
    float inv = (sv > 0.f) ? 1.f/sv : 0.f;
    agg2[(long)i*ENC_ + c] = toB(acc*inv);
}

// ---------------- residual RMSNorm: x = rmsnorm(x + a, g)  (in-place-safe)
__launch_bounds__(128)
__global__ void rms2_k(bf16* __restrict__ x, const bf16* __restrict__ a,
                       const float* __restrict__ g){
    int i = blockIdx.x, t = threadIdx.x;
    __shared__ float red[128];
    float r[4]; float ss = 0.f;
    long base = (long)i*ENC_ + t*4;
    #pragma unroll
    for (int j = 0; j < 4; j++){ float v = toF(x[base+j]) + toF(a[base+j]); r[j] = v; ss += v*v; }
    red[t] = ss; __syncthreads();
    for (int s2 = 64; s2 > 0; s2 >>= 1){ if (t < s2) red[t] += red[t+s2]; __syncthreads(); }
    float sc = rsqrtf(red[0]/512.f + 1e-6f);
    #pragma unroll
    for (int j = 0; j < 4; j++) x[base+j] = toB(r[j]*sc*g[t*4 + j]);
}

// ---------------- final residual RMSNorm -> f32 d_out
__launch_bounds__(128)
__global__ void rms_k(const bf16* __restrict__ x, const bf16* __restrict__ y,
                      const float* __restrict__ g, float* __restrict__ out){
    int i = blockIdx.x, t = threadIdx.x;
    __shared__ float red[128];
    float r[4]; float ss = 0.f;
    long base = (long)i*ENC_ + t*4;
    #pragma unroll
    for (int j = 0; j < 4; j++){ float v = toF(x[base+j]) + toF(y[base+j]); r[j] = v; ss += v*v; }
    red[t] = ss; __syncthreads();
    for (int s2 = 64; s2 > 0; s2 >>= 1){ if (t < s2) red[t] += red[t+s2]; __syncthreads(); }
    float sc = rsqrtf(red[0]/512.f + 1e-6f);
    #pragma unroll
    for (int j = 0; j < 4; j++) out[base+j] = r[j]*sc*g[t*4 + j];
}

// ============================================================== launcher
// ws arena (~60.0 MB):
//  R1 [0, 24M): qkvh [N,768]bf16 -> hbuf [8192,HIDP]bf16
//  R2 [24M, 40M): x1 bf16 (in-place -> x2)
//  R3 [40M, 56M): agg2 bf16 -> y bf16
//  smalls: sfb, snode, wcomb, sbias, cnt, cur, off1, off2, el1, el2, WfrT, WattnT
// Big BT weights live in d_out's fringe region (dead until the final GEMM).
extern "C" void kernel_launch(void* const* d_in, const int* in_sizes, int n_in,
                              void* d_out, int out_size, void* d_ws, size_t ws_size,
                              hipStream_t stream){
    const float* root  = (const float*)d_in[0];
    const float* fb    = (const float*)d_in[1];
    const int*   fbidx = (const int*)d_in[2];   // [0..E1)=j, [E1..2E1)=i
    const float* fmaps = (const float*)d_in[3];
    const int*   rfi   = (const int*)d_in[4];
    const int*   reidx = (const int*)d_in[5];   // [0..E2)=sj, [E2..2E2)=si
    const float* rattr = (const float*)d_in[6];
    const float* Wc2x  = (const float*)d_in[7];
    const float* bc2x  = (const float*)d_in[8];
    const float* Wx2c  = (const float*)d_in[9];
    const float* bx2c  = (const float*)d_in[10];
    const float* Wattn = (const float*)d_in[11];
    const float* battn = (const float*)d_in[12];
    const float* Wqkv  = (const float*)d_in[13];
    const float* bqkv  = (const float*)d_in[14];
    const float* Wgate = (const float*)d_in[15];
    const float* Wup   = (const float*)d_in[16];
    const float* Wout  = (const float*)d_in[17];
    const float* Wfr   = (const float*)d_in[18];
    const float* bfr   = (const float*)d_in[19];
    const float* gnode = (const float*)d_in[20];
    const float* groot = (const float*)d_in[21];
    const float* gffn  = (const float*)d_in[22];

    float* out_x  = (float*)d_out;
    float* out_fr = out_x + (long)N_*ENC_;

    // BT weights in dead fringe region of d_out
    char* frb = (char*)d_out + 33554432;
    bf16* WqkvT = (bf16*)(frb);                 // [1536,512]  1,572,864 B
    bf16* WgateT= (bf16*)(frb + 1572864);       // [1365,512]  1,397,760 B
    bf16* WupT  = (bf16*)(frb + 2970624);       // [1365,512]  1,397,760 B
    bf16* WoutT = (bf16*)(frb + 4368384);       // [512,HIDP]  1,409,024 B

    char* ws = (char*)d_ws;
    bf16*  qkvh  = (bf16*)(ws);                    // R1
    bf16*  hbuf  = (bf16*)(ws);                    // R1 (after qkv dead)
    bf16*  x1    = (bf16*)(ws + 25165824);         // R2
    bf16*  agg2  = (bf16*)(ws + 41943040);         // R3
    bf16*  yb    = agg2;
    float* sfb   = (float*)(ws + 58720256);
    float* snode = (float*)(ws + 60817408);
    float* wcomb = (float*)(ws + 61341696);
    float* sbias = (float*)(ws + 61358080);
    int*   cnt   = (int*)  (ws + 61358336);
    int*   cur   = (int*)  (ws + 61423872);
    int*   off1  = (int*)  (ws + 61489408);
    int*   off2  = (int*)  (ws + 61555200);
    int*   el1   = (int*)  (ws + 61620992);
    int*   el2   = (int*)  (ws + 62145280);
    bf16*  WfrT  = (bf16*)(ws + 62669568);         // [256,512] 262,144 B
    bf16*  WattnT= (bf16*)(ws + 62931712);         // [8,256]   4,096 B

    // ---- weight prep (bf16 transposed)
    prepT_k<<<CDIV(1536*512,256),256,0,stream>>>(Wqkv,  WqkvT, 1536, 512, 512);
    prepT_k<<<CDIV(1365*512,256),256,0,stream>>>(Wgate, WgateT,1365, 512, 512);
    prepT_k<<<CDIV(1365*512,256),256,0,stream>>>(Wup,   WupT,  1365, 512, 512);
    prepT_k<<<CDIV(512*HIDP,256),256,0,stream>>>(Wout,  WoutT, 512, HID_, HIDP);
    prepT_k<<<CDIV(256*512,256),256,0,stream>>>(Wfr,   WfrT,  256, 512, 512);
    prepT_k<<<CDIV(8*256,256),256,0,stream>>>(Wattn, WattnT, 8, 256, 256);

    // ---- CSR builds
    hipMemsetAsync(cnt, 0, N_*4, stream);
    count_k<<<CDIV(E1_,256),256,0,stream>>>(fbidx + E1_, cnt, E1_);
    scan_k<<<1,1024,0,stream>>>(cnt, off1, cur, N_);
    fill_k<<<CDIV(E1_,256),256,0,stream>>>(fbidx + E1_, cur, el1, E1_);
    hipMemsetAsync(cnt, 0, N_*4, stream);
    count_k<<<CDIV(E2_,256),256,0,stream>>>(reidx + E2_, cnt, E2_);
    scan_k<<<1,1024,0,stream>>>(cnt, off2, cur, N_);
    fill_k<<<CDIV(E2_,256),256,0,stream>>>(reidx + E2_, cur, el2, E2_);

    // ---- stage-1 precomputes
    wcomb_k<<<16,256,0,stream>>>(Wx2c, Wattn, bx2c, battn, wcomb, sbias);
    snode_k<<<CDIV(N_*8,256),256,0,stream>>>(root, wcomb, sbias, snode);
    { dim3 g(1, CDIV(M_,128));   // sfb = fb @ W_attn[:256]  [M,8] f32 (MFMA)
      mgemm_k<float,0,0,0,0><<<g,256,0,stream>>>(fb, WattnT, nullptr, nullptr, sfb,
                                                 nullptr, nullptr, M_, 8, 256, 256, 256, 8); }
    stage1_k<<<N_,256,0,stream>>>(root, fb, sfb, snode, fbidx, off1, el1,
                                  Wc2x, bc2x, gnode, x1);

    // ---- stage 2: two head-group passes
    for (int p = 0; p < 2; p++){
        dim3 g(CDIV(768,128), CDIV(N_,128));
        mgemm_k<bf16,0,0,0,1><<<g,256,0,stream>>>(x1, WqkvT + (long)p*768*512, nullptr,
                                                  bqkv + p*768, qkvh, nullptr, nullptr,
                                                  N_, 768, 512, 512, 512, 768);
        stage2_k<<<N_,256,0,stream>>>(qkvh, rattr, reidx, off2, el2, agg2 + p*256);
    }
    rms2_k<<<N_,128,0,stream>>>(x1, agg2, groot);   // x1 -> x2 in-place

    // ---- FFN in two row-chunks (R1 holds h-chunk, rows padded to HIDP)
    for (int rc = 0; rc < 2; rc++){
        long ro = (long)rc*8192;
        { dim3 g(CDIV(HID_,128), CDIV(8192,128));
          mgemm_k<bf16,1,0,0,1><<<g,256,0,stream>>>(x1 + ro*ENC_, WgateT, WupT, nullptr,
                                                    hbuf, nullptr, nullptr,
                                                    8192, HID_, 512, 512, 512, HIDP); }
        { dim3 g(CDIV(512,128), CDIV(8192,128));
          mgemm_k<bf16,0,0,0,1><<<g,256,0,stream>>>(hbuf, WoutT, nullptr, nullptr,
                                                    yb + ro*ENC_, nullptr, nullptr,
                                                    8192, 512, HID_, HIDP, HIDP, 512); }
    }
    rms_k<<<N_,128,0,stream>>>(x1, yb, gffn, out_x);

    // ---- fringe decode (gather f32 rows of out_x, multiply fringe_maps)
    { dim3 g(CDIV(256,128), CDIV(F_,128));
      mgemm_k<float,0,1,1,0><<<g,256,0,stream>>>(out_x, WfrT, nullptr, bfr, out_fr,
                                                 rfi, fmaps, F_, 256, 512, 512, 512, 256); }
}